// Round 12
// baseline (348.926 us; speedup 1.0000x reference)
//
#include <hip/hip_runtime.h>
#include <hip/hip_fp16.h>
#include <math.h>

#define NN 100000
#define EE 1600000
#define NEG 0.2f
#define NB 98     // ceil(NN/1024) scan blocks
#define STRIP 128 // nodes per gemm1 block
#define GB 782    // gemm blocks = ceil(NN/STRIP)
#define HB 6250   // hist blocks = ceil(EE/256)

typedef _Float16 fh8 __attribute__((ext_vector_type(8)));
typedef float f32x4 __attribute__((ext_vector_type(4)));
typedef float f32x2 __attribute__((ext_vector_type(2)));

__device__ __forceinline__ float lrelu(float v) { return v > 0.f ? v : NEG * v; }

// unpack 16 fp8 (OCP e4m3) + weighted accumulate: 8 cvt_pk + 16 fma
__device__ __forceinline__ void fma16_fp8(uint4 r, float w, float* acc)
{
    f32x2 p0 = __builtin_amdgcn_cvt_pk_f32_fp8(r.x, false);
    f32x2 p1 = __builtin_amdgcn_cvt_pk_f32_fp8(r.x, true);
    f32x2 p2 = __builtin_amdgcn_cvt_pk_f32_fp8(r.y, false);
    f32x2 p3 = __builtin_amdgcn_cvt_pk_f32_fp8(r.y, true);
    f32x2 p4 = __builtin_amdgcn_cvt_pk_f32_fp8(r.z, false);
    f32x2 p5 = __builtin_amdgcn_cvt_pk_f32_fp8(r.z, true);
    f32x2 p6 = __builtin_amdgcn_cvt_pk_f32_fp8(r.w, false);
    f32x2 p7 = __builtin_amdgcn_cvt_pk_f32_fp8(r.w, true);
    acc[0]  = fmaf(w, p0.x, acc[0]);  acc[1]  = fmaf(w, p0.y, acc[1]);
    acc[2]  = fmaf(w, p1.x, acc[2]);  acc[3]  = fmaf(w, p1.y, acc[3]);
    acc[4]  = fmaf(w, p2.x, acc[4]);  acc[5]  = fmaf(w, p2.y, acc[5]);
    acc[6]  = fmaf(w, p3.x, acc[6]);  acc[7]  = fmaf(w, p3.y, acc[7]);
    acc[8]  = fmaf(w, p4.x, acc[8]);  acc[9]  = fmaf(w, p4.y, acc[9]);
    acc[10] = fmaf(w, p5.x, acc[10]); acc[11] = fmaf(w, p5.y, acc[11]);
    acc[12] = fmaf(w, p6.x, acc[12]); acc[13] = fmaf(w, p6.y, acc[13]);
    acc[14] = fmaf(w, p7.x, acc[14]); acc[15] = fmaf(w, p7.y, acc[15]);
}

// extract head-h weight from packed entry {src, w01(half2), w23(half2), pad}
__device__ __forceinline__ float ewgt(const int4& e, int head)
{
    uint p = (head < 2) ? (uint)e.y : (uint)e.z;
    float2 f = __half22float2(*(const __half2*)&p);
    return (head & 1) ? f.y : f.x;
}

// ---------------- prep: pack W1 (MFMA A-frag order) + BN affine + zero counts ----------------
__global__ __launch_bounds__(256) void prep_kernel(
    const float* __restrict__ W1,
    const float* __restrict__ b1, const float* __restrict__ gamma,
    const float* __restrict__ beta, const float* __restrict__ rmean,
    const float* __restrict__ rvar,
    _Float16* __restrict__ W1f, float* __restrict__ nA, float* __restrict__ nB,
    int* __restrict__ counts)
{
    int t = blockIdx.x * 256 + threadIdx.x;   // grid = 128 blocks
    if (t < 64 * 64) {
        int l = t & 63, frag = t >> 6;
        int kk = frag & 3, ft = (frag >> 2) & 3, w = frag >> 4;
        int feat = w * 64 + ft * 16 + (l & 15);
        int kbase = kk * 32 + (l >> 4) * 8;
        _Float16 v[8];
#pragma unroll
        for (int i = 0; i < 8; i++) v[i] = (_Float16)W1[(size_t)(kbase + i) * 256 + feat];
        *(fh8*)&W1f[(size_t)t * 8] = *(fh8*)v;
    } else if (t < 64 * 64 + 256) {
        int f = t - 64 * 64;
        float scale = gamma[f] * rsqrtf(rvar[f] + 1e-5f);
        nA[f] = scale;
        nB[f] = (b1[f] - rmean[f]) * scale + beta[f];
    }
    for (int i = t; i < NN; i += 128 * 256) counts[i] = 0;
}

// ---------------- fused GEMM1 (MFMA) + edge histogram; h1 stored fp8 e4m3 ----------------
__global__ __launch_bounds__(256) void gemm1_hist(
    const float* __restrict__ x, const _Float16* __restrict__ W1f,
    const float* __restrict__ attS1, const float* __restrict__ attD1,
    uint* __restrict__ h1, float* __restrict__ asrc1, float* __restrict__ adst1,
    const int* __restrict__ ei, int* __restrict__ counts)
{
    const int bid = blockIdx.x;
    const int tid = threadIdx.x;
    if (bid >= GB) {
        int e = (bid - GB) * 256 + tid;
        if (e < EE) atomicAdd(&counts[ei[EE + e]], 1);
        return;
    }

    __shared__ _Float16 xh[STRIP][136];
    const int lane = tid & 63;
    const int w    = tid >> 6;            // wave id == head id
    const int base = bid * STRIP;

#pragma unroll
    for (int it = 0; it < 2; ++it) {
        int slot = tid + it * 256;
        int node = slot >> 2;
        int k0   = (slot & 3) * 32;
        int gnode = base + node;
        float4 buf[8];
        if (gnode < NN) {
            const float4* src = (const float4*)(x + (size_t)gnode * 128 + k0);
#pragma unroll
            for (int j = 0; j < 8; j++) buf[j] = src[j];
        } else {
#pragma unroll
            for (int j = 0; j < 8; j++) buf[j] = make_float4(0.f, 0.f, 0.f, 0.f);
        }
        _Float16* dst = &xh[node][k0];
#pragma unroll
        for (int j = 0; j < 8; j++) {
            dst[j * 4 + 0] = (_Float16)buf[j].x;
            dst[j * 4 + 1] = (_Float16)buf[j].y;
            dst[j * 4 + 2] = (_Float16)buf[j].z;
            dst[j * 4 + 3] = (_Float16)buf[j].w;
        }
    }
    __syncthreads();

    fh8 afrag[4][4];
    const fh8* wf = (const fh8*)W1f;
#pragma unroll
    for (int ft = 0; ft < 4; ft++)
#pragma unroll
        for (int kk = 0; kk < 4; kk++)
            afrag[ft][kk] = wf[((w * 4 + ft) * 4 + kk) * 64 + lane];

    const int nrow = lane & 15;
    const int kq   = lane >> 4;

    float attSv[4][4], attDv[4][4];
#pragma unroll
    for (int ft = 0; ft < 4; ft++)
#pragma unroll
        for (int r = 0; r < 4; r++) {
            int feat = w * 64 + ft * 16 + kq * 4 + r;
            attSv[ft][r] = attS1[feat];
            attDv[ft][r] = attD1[feat];
        }

    for (int g = 0; g < STRIP / 16; ++g) {
        fh8 b[4];
#pragma unroll
        for (int kk = 0; kk < 4; kk++)
            b[kk] = *(const fh8*)&xh[g * 16 + nrow][kk * 32 + kq * 8];

        f32x4 d[4];
#pragma unroll
        for (int ft = 0; ft < 4; ft++) {
            d[ft] = (f32x4){0.f, 0.f, 0.f, 0.f};
#pragma unroll
            for (int kk = 0; kk < 4; kk++)
                d[ft] = __builtin_amdgcn_mfma_f32_16x16x32_f16(afrag[ft][kk], b[kk], d[ft], 0, 0, 0);
        }

        int gnode = base + g * 16 + nrow;
        if (gnode < NN) {
            float ps = 0.f, pd = 0.f;
#pragma unroll
            for (int ft = 0; ft < 4; ft++) {
                float v0 = d[ft][0], v1 = d[ft][1], v2 = d[ft][2], v3 = d[ft][3];
                ps = fmaf(v0, attSv[ft][0], ps); pd = fmaf(v0, attDv[ft][0], pd);
                ps = fmaf(v1, attSv[ft][1], ps); pd = fmaf(v1, attDv[ft][1], pd);
                ps = fmaf(v2, attSv[ft][2], ps); pd = fmaf(v2, attDv[ft][2], pd);
                ps = fmaf(v3, attSv[ft][3], ps); pd = fmaf(v3, attDv[ft][3], pd);
                uint pk = 0;
                pk = __builtin_amdgcn_cvt_pk_fp8_f32(v0, v1, pk, false);
                pk = __builtin_amdgcn_cvt_pk_fp8_f32(v2, v3, pk, true);
                h1[(size_t)gnode * 64 + w * 16 + ft * 4 + kq] = pk;
            }
            ps += __shfl_xor(ps, 16); ps += __shfl_xor(ps, 32);
            pd += __shfl_xor(pd, 16); pd += __shfl_xor(pd, 32);
            if (kq == 0) { asrc1[gnode * 4 + w] = ps; adst1[gnode * 4 + w] = pd; }
        }
    }
}

// ---------------- scans ----------------
__global__ __launch_bounds__(256) void scan1_kernel(const int* __restrict__ counts, int* __restrict__ bsum)
{
    __shared__ int red[256];
    int t = threadIdx.x;
    int i0 = blockIdx.x * 1024 + t * 4;
    int s = 0;
    if (i0 + 3 < NN) {
        int4 v = *(const int4*)&counts[i0];
        s = v.x + v.y + v.z + v.w;
    } else {
#pragma unroll
        for (int j = 0; j < 4; j++) { int i = i0 + j; if (i < NN) s += counts[i]; }
    }
    red[t] = s;
    __syncthreads();
    for (int off = 128; off > 0; off >>= 1) {
        if (t < off) red[t] += red[t + off];
        __syncthreads();
    }
    if (t == 0) bsum[blockIdx.x] = red[0];
}

__global__ void scan2_kernel(const int* __restrict__ bsum, int* __restrict__ bbase, int* __restrict__ offs)
{
    __shared__ int sh[128];
    int t = threadIdx.x;
    int v = (t < NB) ? bsum[t] : 0;
    sh[t] = v;
    __syncthreads();
    for (int off = 1; off < 128; off <<= 1) {
        int u = (t >= off) ? sh[t - off] : 0;
        __syncthreads();
        sh[t] += u;
        __syncthreads();
    }
    if (t < NB) bbase[t] = sh[t] - v;
    if (t == 0) offs[NN] = EE;
}

__global__ __launch_bounds__(256) void scan3_kernel(const int* __restrict__ counts,
                                                    const int* __restrict__ bbase,
                                                    int* __restrict__ offs, int* __restrict__ cursor)
{
    __shared__ int sh[256];
    int t = threadIdx.x;
    int i0 = blockIdx.x * 1024 + t * 4;
    int c[4];
    int s = 0;
#pragma unroll
    for (int j = 0; j < 4; j++) { int i = i0 + j; c[j] = (i < NN) ? counts[i] : 0; s += c[j]; }
    sh[t] = s;
    __syncthreads();
    for (int off = 1; off < 256; off <<= 1) {
        int u = (t >= off) ? sh[t - off] : 0;
        __syncthreads();
        sh[t] += u;
        __syncthreads();
    }
    int run = bbase[blockIdx.x] + sh[t] - s;
    if (i0 + 3 < NN) {
        int4 o;
        o.x = run; run += c[0];
        o.y = run; run += c[1];
        o.z = run; run += c[2];
        o.w = run;
        *(int4*)&offs[i0] = o;
        *(int4*)&cursor[i0] = o;
    } else {
#pragma unroll
        for (int j = 0; j < 4; j++) { int i = i0 + j; if (i < NN) { offs[i] = run; cursor[i] = run; run += c[j]; } }
    }
}

// ---------------- scatter: CSR build, packed 16B entry {src, w as 4xfp16} ----------------
__global__ void scatter_kernel(const int* __restrict__ ei,
                               const float* __restrict__ asrc1, const float* __restrict__ adst1,
                               int* __restrict__ cursor, int4* __restrict__ csr)
{
    int e = blockIdx.x * 256 + threadIdx.x;
    if (e >= EE) return;
    int s = ei[e], d = ei[EE + e];
    int pos = atomicAdd(&cursor[d], 1);
    float4 as = *(const float4*)&asrc1[(size_t)s * 4];
    float4 ad = *(const float4*)&adst1[(size_t)d * 4];
    __half2 w01 = __floats2half2_rn(__expf(lrelu(as.x + ad.x)), __expf(lrelu(as.y + ad.y)));
    __half2 w23 = __floats2half2_rn(__expf(lrelu(as.z + ad.z)), __expf(lrelu(as.w + ad.w)));
    int4 ent;
    ent.x = s;
    ent.y = *(const int*)&w01;
    ent.z = *(const int*)&w23;
    ent.w = 0;
    csr[pos] = ent;
}

// ---------------- agg1 + node2-epilogue: one wave per node; 4 edge slots x 2 unroll ----------------
// lane = slot*16 + fl (slot=lane>>4 in 0..3, fl=lane&15). Each lane loads uint4 = 16B of the
// 256B fp8 row -> 8 rows in flight per wave (2x R11's MLP). Weights precomputed (no dependent
// exp in loop). Reduce slots via xor16+xor32; epilogue per-lane covers feats fl*16..fl*16+15.
__global__ __launch_bounds__(256) void agg1_node2(
    const int* __restrict__ offs, const int4* __restrict__ csr,
    const uint* __restrict__ h1,
    const float* __restrict__ nA, const float* __restrict__ nB,
    const float* __restrict__ W2, const float* __restrict__ attS2, const float* __restrict__ attD2,
    float4* __restrict__ pk2)
{
    int wid  = (blockIdx.x * 256 + threadIdx.x) >> 6;
    int lane = threadIdx.x & 63;
    if (wid >= NN) return;
    int lo = offs[wid], hi = offs[wid + 1];
    const int slot = lane >> 4;    // edge slot 0..3
    const int fl   = lane & 15;    // 16B block of row: feats fl*16 .. fl*16+15
    const int head = fl >> 2;      // 64 feats/head, 16 feats/lane

    float acc[16];
#pragma unroll
    for (int j = 0; j < 16; j++) acc[j] = 0.f;
    float wsum = 0.f;

    const uint4* h1v = (const uint4*)h1;   // row = 16 x uint4

    int base = lo;
    for (; base + 7 < hi; base += 8) {
        int idx0 = base + slot;
        int idx1 = base + 4 + slot;
        int4 e0 = csr[idx0];
        int4 e1 = csr[idx1];
        uint4 r0 = h1v[(size_t)e0.x * 16 + fl];
        uint4 r1 = h1v[(size_t)e1.x * 16 + fl];
        float w0 = ewgt(e0, head);
        float w1 = ewgt(e1, head);
        fma16_fp8(r0, w0, acc);
        fma16_fp8(r1, w1, acc);
        wsum += w0 + w1;
    }
    for (; base < hi; base += 4) {
        int idx = base + slot;
        float w = 0.f;
        uint4 r = make_uint4(0, 0, 0, 0);
        if (idx < hi) {
            int4 e = csr[idx];
            w = ewgt(e, head);
            r = h1v[(size_t)e.x * 16 + fl];
        }
        fma16_fp8(r, w, acc);
        wsum += w;
    }

    // merge 4 edge slots (bits 4,5 of lane): all lanes end with full sums
#pragma unroll
    for (int j = 0; j < 16; j++) {
        acc[j] += __shfl_xor(acc[j], 16);
        acc[j] += __shfl_xor(acc[j], 32);
    }
    wsum += __shfl_xor(wsum, 16);
    wsum += __shfl_xor(wsum, 32);

    float inv = 1.f / (wsum + 1e-16f);

    // fused node2 epilogue: lane fl holds feats fl*16..fl*16+15 (duplicated across slots)
    float c0 = 0.f, c1 = 0.f;
#pragma unroll
    for (int q = 0; q < 4; ++q) {
        float4 na = *(const float4*)&nA[fl * 16 + q * 4];
        float4 nb = *(const float4*)&nB[fl * 16 + q * 4];
        float naa[4] = {na.x, na.y, na.z, na.w};
        float nba[4] = {nb.x, nb.y, nb.z, nb.w};
#pragma unroll
        for (int j = 0; j < 4; j++) {
            int f = fl * 16 + q * 4 + j;
            float g = acc[q * 4 + j] * inv;
            float u = fmaf(g, naa[j], nba[j]);
            float t = u > 0.f ? u : (__expf(u) - 1.f);
            c0 = fmaf(t, W2[f * 2],     c0);
            c1 = fmaf(t, W2[f * 2 + 1], c1);
        }
    }
    // reduce over 16 feature blocks (bits 0-3); slots already merged
    c0 += __shfl_xor(c0, 1); c0 += __shfl_xor(c0, 2); c0 += __shfl_xor(c0, 4); c0 += __shfl_xor(c0, 8);
    c1 += __shfl_xor(c1, 1); c1 += __shfl_xor(c1, 2); c1 += __shfl_xor(c1, 4); c1 += __shfl_xor(c1, 8);

    if (lane == 0) {
        float as2 = c0 * attS2[0] + c1 * attS2[1];
        float ad2 = c0 * attD2[0] + c1 * attD2[1];
        pk2[wid] = make_float4(as2, ad2, c0, c1);
    }
}

// ---------------- agg2: 8 lanes per node, 16B pk2 gather + fused log_softmax ----------------
__global__ __launch_bounds__(256) void agg2_kernel(
    const int* __restrict__ offs, const int4* __restrict__ csr,
    const float4* __restrict__ pk2, const float* __restrict__ b2,
    float* __restrict__ out)
{
    int wid  = (blockIdx.x * 256 + threadIdx.x) >> 6;
    int lane = threadIdx.x & 63;
    int grp  = lane >> 3;
    int sub  = lane & 7;
    int n = wid * 8 + grp;
    if (n >= NN) return;
    int lo = offs[n], hi = offs[n + 1];
    float ad = pk2[n].y;

    float n0 = 0.f, n1 = 0.f, ws = 0.f;
    for (int i = lo + sub; i < hi; i += 8) {
        int s = csr[i].x;
        float4 p = pk2[s];
        float w = __expf(lrelu(p.x + ad));
        n0 = fmaf(w, p.z, n0);
        n1 = fmaf(w, p.w, n1);
        ws += w;
    }
    n0 += __shfl_xor(n0, 1); n0 += __shfl_xor(n0, 2); n0 += __shfl_xor(n0, 4);
    n1 += __shfl_xor(n1, 1); n1 += __shfl_xor(n1, 2); n1 += __shfl_xor(n1, 4);
    ws += __shfl_xor(ws, 1); ws += __shfl_xor(ws, 2); ws += __shfl_xor(ws, 4);

    if (sub == 0) {
        float inv = 1.f / (ws + 1e-16f);
        float v0 = n0 * inv + b2[0];
        float v1 = n1 * inv + b2[1];
        float m = fmaxf(v0, v1);
        float lse = m + log1pf(__expf(fminf(v0, v1) - m));
        *(float2*)&out[(size_t)n * 2] = make_float2(v0 - lse, v1 - lse);
    }
}

extern "C" void kernel_launch(void* const* d_in, const int* in_sizes, int n_in,
                              void* d_out, int out_size, void* d_ws, size_t ws_size,
                              hipStream_t stream)
{
    const float* x     = (const float*)d_in[0];
    const int*   ei    = (const int*)d_in[1];
    const float* W1    = (const float*)d_in[2];
    const float* attS1 = (const float*)d_in[3];
    const float* attD1 = (const float*)d_in[4];
    const float* b1    = (const float*)d_in[5];
    const float* gamma = (const float*)d_in[6];
    const float* beta  = (const float*)d_in[7];
    const float* rmean = (const float*)d_in[8];
    const float* rvar  = (const float*)d_in[9];
    const float* W2    = (const float*)d_in[10];
    const float* attS2 = (const float*)d_in[11];
    const float* attD2 = (const float*)d_in[12];
    const float* b2    = (const float*)d_in[13];
    float* out = (float*)d_out;

    float* f = (float*)d_ws;
    uint* h1      = (uint*)f;                    // N*64 dwords (fp8 rows, 256B each)
    float* asrc1  = f + (size_t)NN * 64;         // N*4
    float* adst1  = asrc1 + (size_t)NN * 4;      // N*4
    _Float16* W1f = (_Float16*)(adst1 + (size_t)NN * 4);  // 32768 halfs = 16384 floats
    float* nA     = adst1 + (size_t)NN * 4 + 16384;       // 256
    float* nB     = nA + 256;                    // 256
    float4* pk2   = (float4*)(nB + 256);         // N float4 (16B aligned)
    int4* csr     = (int4*)(pk2 + NN);           // E int4  (16B aligned)
    int* counts   = (int*)(csr + EE);            // N [zeroed in prep]
    int* offs     = counts + NN;                 // N+1
    int* cursor   = offs + (NN + 1);             // N
    int* bsum     = cursor + NN;                 // NB
    int* bbase    = bsum + NB;                   // NB

    prep_kernel<<<128, 256, 0, stream>>>(W1, b1, gamma, beta, rmean, rvar, W1f, nA, nB, counts);

    gemm1_hist<<<GB + HB, 256, 0, stream>>>(x, W1f, attS1, attD1, h1, asrc1, adst1, ei, counts);

    scan1_kernel<<<NB, 256, 0, stream>>>(counts, bsum);
    scan2_kernel<<<1, 128, 0, stream>>>(bsum, bbase, offs);
    scan3_kernel<<<NB, 256, 0, stream>>>(counts, bbase, offs, cursor);

    scatter_kernel<<<HB, 256, 0, stream>>>(ei, asrc1, adst1, cursor, csr);

    agg1_node2<<<(NN + 3) / 4, 256, 0, stream>>>(offs, csr, h1, nA, nB, W2, attS2, attD2, pk2);

    agg2_kernel<<<(NN + 31) / 32, 256, 0, stream>>>(offs, csr, pk2, b2, out);
}

// Round 13
// 275.782 us; speedup vs baseline: 1.2652x; 1.2652x over previous
//
#include <hip/hip_runtime.h>
#include <hip/hip_fp16.h>
#include <math.h>

#define NN 100000
#define EE 1600000
#define NEG 0.2f
#define NB 98     // ceil(NN/1024) scan blocks
#define STRIP 128 // nodes per gemm1 block
#define GB 782    // gemm blocks = ceil(NN/STRIP)
#define HB 6250   // hist blocks = ceil(EE/256)

typedef _Float16 fh8 __attribute__((ext_vector_type(8)));
typedef float f32x4 __attribute__((ext_vector_type(4)));
typedef float f32x2 __attribute__((ext_vector_type(2)));

__device__ __forceinline__ float lrelu(float v) { return v > 0.f ? v : NEG * v; }

// unpack 8 fp8 (OCP e4m3) + weighted accumulate: 4 cvt_pk + 8 fma
__device__ __forceinline__ void fma8_fp8(uint2 r, float w, float* acc)
{
    f32x2 p0 = __builtin_amdgcn_cvt_pk_f32_fp8(r.x, false);
    f32x2 p1 = __builtin_amdgcn_cvt_pk_f32_fp8(r.x, true);
    f32x2 p2 = __builtin_amdgcn_cvt_pk_f32_fp8(r.y, false);
    f32x2 p3 = __builtin_amdgcn_cvt_pk_f32_fp8(r.y, true);
    acc[0] = fmaf(w, p0.x, acc[0]); acc[1] = fmaf(w, p0.y, acc[1]);
    acc[2] = fmaf(w, p1.x, acc[2]); acc[3] = fmaf(w, p1.y, acc[3]);
    acc[4] = fmaf(w, p2.x, acc[4]); acc[5] = fmaf(w, p2.y, acc[5]);
    acc[6] = fmaf(w, p3.x, acc[6]); acc[7] = fmaf(w, p3.y, acc[7]);
}

// extract head-h weight from packed entry {src, w01(half2), w23(half2), pad}
__device__ __forceinline__ float ewgt(const int4& e, int head)
{
    uint p = (head < 2) ? (uint)e.y : (uint)e.z;
    float2 f = __half22float2(*(const __half2*)&p);
    return (head & 1) ? f.y : f.x;
}

// ---------------- prep: pack W1 (MFMA A-frag order) + BN affine + zero counts ----------------
__global__ __launch_bounds__(256) void prep_kernel(
    const float* __restrict__ W1,
    const float* __restrict__ b1, const float* __restrict__ gamma,
    const float* __restrict__ beta, const float* __restrict__ rmean,
    const float* __restrict__ rvar,
    _Float16* __restrict__ W1f, float* __restrict__ nA, float* __restrict__ nB,
    int* __restrict__ counts)
{
    int t = blockIdx.x * 256 + threadIdx.x;   // grid = 128 blocks
    if (t < 64 * 64) {
        int l = t & 63, frag = t >> 6;
        int kk = frag & 3, ft = (frag >> 2) & 3, w = frag >> 4;
        int feat = w * 64 + ft * 16 + (l & 15);
        int kbase = kk * 32 + (l >> 4) * 8;
        _Float16 v[8];
#pragma unroll
        for (int i = 0; i < 8; i++) v[i] = (_Float16)W1[(size_t)(kbase + i) * 256 + feat];
        *(fh8*)&W1f[(size_t)t * 8] = *(fh8*)v;
    } else if (t < 64 * 64 + 256) {
        int f = t - 64 * 64;
        float scale = gamma[f] * rsqrtf(rvar[f] + 1e-5f);
        nA[f] = scale;
        nB[f] = (b1[f] - rmean[f]) * scale + beta[f];
    }
    for (int i = t; i < NN; i += 128 * 256) counts[i] = 0;
}

// ---------------- fused GEMM1 (MFMA) + edge histogram; h1 stored fp8 e4m3 ----------------
__global__ __launch_bounds__(256) void gemm1_hist(
    const float* __restrict__ x, const _Float16* __restrict__ W1f,
    const float* __restrict__ attS1, const float* __restrict__ attD1,
    uint* __restrict__ h1, float* __restrict__ asrc1, float* __restrict__ adst1,
    const int* __restrict__ ei, int* __restrict__ counts)
{
    const int bid = blockIdx.x;
    const int tid = threadIdx.x;
    if (bid >= GB) {
        int e = (bid - GB) * 256 + tid;
        if (e < EE) atomicAdd(&counts[ei[EE + e]], 1);
        return;
    }

    __shared__ _Float16 xh[STRIP][136];
    const int lane = tid & 63;
    const int w    = tid >> 6;            // wave id == head id
    const int base = bid * STRIP;

#pragma unroll
    for (int it = 0; it < 2; ++it) {
        int slot = tid + it * 256;
        int node = slot >> 2;
        int k0   = (slot & 3) * 32;
        int gnode = base + node;
        float4 buf[8];
        if (gnode < NN) {
            const float4* src = (const float4*)(x + (size_t)gnode * 128 + k0);
#pragma unroll
            for (int j = 0; j < 8; j++) buf[j] = src[j];
        } else {
#pragma unroll
            for (int j = 0; j < 8; j++) buf[j] = make_float4(0.f, 0.f, 0.f, 0.f);
        }
        _Float16* dst = &xh[node][k0];
#pragma unroll
        for (int j = 0; j < 8; j++) {
            dst[j * 4 + 0] = (_Float16)buf[j].x;
            dst[j * 4 + 1] = (_Float16)buf[j].y;
            dst[j * 4 + 2] = (_Float16)buf[j].z;
            dst[j * 4 + 3] = (_Float16)buf[j].w;
        }
    }
    __syncthreads();

    fh8 afrag[4][4];
    const fh8* wf = (const fh8*)W1f;
#pragma unroll
    for (int ft = 0; ft < 4; ft++)
#pragma unroll
        for (int kk = 0; kk < 4; kk++)
            afrag[ft][kk] = wf[((w * 4 + ft) * 4 + kk) * 64 + lane];

    const int nrow = lane & 15;
    const int kq   = lane >> 4;

    float attSv[4][4], attDv[4][4];
#pragma unroll
    for (int ft = 0; ft < 4; ft++)
#pragma unroll
        for (int r = 0; r < 4; r++) {
            int feat = w * 64 + ft * 16 + kq * 4 + r;
            attSv[ft][r] = attS1[feat];
            attDv[ft][r] = attD1[feat];
        }

    for (int g = 0; g < STRIP / 16; ++g) {
        fh8 b[4];
#pragma unroll
        for (int kk = 0; kk < 4; kk++)
            b[kk] = *(const fh8*)&xh[g * 16 + nrow][kk * 32 + kq * 8];

        f32x4 d[4];
#pragma unroll
        for (int ft = 0; ft < 4; ft++) {
            d[ft] = (f32x4){0.f, 0.f, 0.f, 0.f};
#pragma unroll
            for (int kk = 0; kk < 4; kk++)
                d[ft] = __builtin_amdgcn_mfma_f32_16x16x32_f16(afrag[ft][kk], b[kk], d[ft], 0, 0, 0);
        }

        int gnode = base + g * 16 + nrow;
        if (gnode < NN) {
            float ps = 0.f, pd = 0.f;
#pragma unroll
            for (int ft = 0; ft < 4; ft++) {
                float v0 = d[ft][0], v1 = d[ft][1], v2 = d[ft][2], v3 = d[ft][3];
                ps = fmaf(v0, attSv[ft][0], ps); pd = fmaf(v0, attDv[ft][0], pd);
                ps = fmaf(v1, attSv[ft][1], ps); pd = fmaf(v1, attDv[ft][1], pd);
                ps = fmaf(v2, attSv[ft][2], ps); pd = fmaf(v2, attDv[ft][2], pd);
                ps = fmaf(v3, attSv[ft][3], ps); pd = fmaf(v3, attDv[ft][3], pd);
                uint pk = 0;
                pk = __builtin_amdgcn_cvt_pk_fp8_f32(v0, v1, pk, false);
                pk = __builtin_amdgcn_cvt_pk_fp8_f32(v2, v3, pk, true);
                h1[(size_t)gnode * 64 + w * 16 + ft * 4 + kq] = pk;
            }
            ps += __shfl_xor(ps, 16); ps += __shfl_xor(ps, 32);
            pd += __shfl_xor(pd, 16); pd += __shfl_xor(pd, 32);
            if (kq == 0) { asrc1[gnode * 4 + w] = ps; adst1[gnode * 4 + w] = pd; }
        }
    }
}

// ---------------- scans ----------------
__global__ __launch_bounds__(256) void scan1_kernel(const int* __restrict__ counts, int* __restrict__ bsum)
{
    __shared__ int red[256];
    int t = threadIdx.x;
    int i0 = blockIdx.x * 1024 + t * 4;
    int s = 0;
    if (i0 + 3 < NN) {
        int4 v = *(const int4*)&counts[i0];
        s = v.x + v.y + v.z + v.w;
    } else {
#pragma unroll
        for (int j = 0; j < 4; j++) { int i = i0 + j; if (i < NN) s += counts[i]; }
    }
    red[t] = s;
    __syncthreads();
    for (int off = 128; off > 0; off >>= 1) {
        if (t < off) red[t] += red[t + off];
        __syncthreads();
    }
    if (t == 0) bsum[blockIdx.x] = red[0];
}

__global__ void scan2_kernel(const int* __restrict__ bsum, int* __restrict__ bbase, int* __restrict__ offs)
{
    __shared__ int sh[128];
    int t = threadIdx.x;
    int v = (t < NB) ? bsum[t] : 0;
    sh[t] = v;
    __syncthreads();
    for (int off = 1; off < 128; off <<= 1) {
        int u = (t >= off) ? sh[t - off] : 0;
        __syncthreads();
        sh[t] += u;
        __syncthreads();
    }
    if (t < NB) bbase[t] = sh[t] - v;
    if (t == 0) offs[NN] = EE;
}

__global__ __launch_bounds__(256) void scan3_kernel(const int* __restrict__ counts,
                                                    const int* __restrict__ bbase,
                                                    int* __restrict__ offs, int* __restrict__ cursor)
{
    __shared__ int sh[256];
    int t = threadIdx.x;
    int i0 = blockIdx.x * 1024 + t * 4;
    int c[4];
    int s = 0;
#pragma unroll
    for (int j = 0; j < 4; j++) { int i = i0 + j; c[j] = (i < NN) ? counts[i] : 0; s += c[j]; }
    sh[t] = s;
    __syncthreads();
    for (int off = 1; off < 256; off <<= 1) {
        int u = (t >= off) ? sh[t - off] : 0;
        __syncthreads();
        sh[t] += u;
        __syncthreads();
    }
    int run = bbase[blockIdx.x] + sh[t] - s;
    if (i0 + 3 < NN) {
        int4 o;
        o.x = run; run += c[0];
        o.y = run; run += c[1];
        o.z = run; run += c[2];
        o.w = run;
        *(int4*)&offs[i0] = o;
        *(int4*)&cursor[i0] = o;
    } else {
#pragma unroll
        for (int j = 0; j < 4; j++) { int i = i0 + j; if (i < NN) { offs[i] = run; cursor[i] = run; run += c[j]; } }
    }
}

// ---------------- scatter: CSR build, packed 16B entry {src, w as 4xfp16} ----------------
__global__ void scatter_kernel(const int* __restrict__ ei,
                               const float* __restrict__ asrc1, const float* __restrict__ adst1,
                               int* __restrict__ cursor, int4* __restrict__ csr)
{
    int e = blockIdx.x * 256 + threadIdx.x;
    if (e >= EE) return;
    int s = ei[e], d = ei[EE + e];
    int pos = atomicAdd(&cursor[d], 1);
    float4 as = *(const float4*)&asrc1[(size_t)s * 4];
    float4 ad = *(const float4*)&adst1[(size_t)d * 4];
    __half2 w01 = __floats2half2_rn(__expf(lrelu(as.x + ad.x)), __expf(lrelu(as.y + ad.y)));
    __half2 w23 = __floats2half2_rn(__expf(lrelu(as.z + ad.z)), __expf(lrelu(as.w + ad.w)));
    int4 ent;
    ent.x = s;
    ent.y = *(const int*)&w01;
    ent.z = *(const int*)&w23;
    ent.w = 0;
    csr[pos] = ent;
}

// ---------------- agg1 + node2-epilogue: one wave per node; fp8 h1 gather ----------------
// R11-proven shape (2 edge slots x 32 lanes, uint2 row loads), now 4-way unrolled:
// 4 independent csr loads + 4 independent row-load pairs per iteration -> 8 rows
// in flight per wave while keeping 2 rows per vmem instruction.
__global__ __launch_bounds__(256) void agg1_node2(
    const int* __restrict__ offs, const int4* __restrict__ csr,
    const uint* __restrict__ h1,
    const float* __restrict__ nA, const float* __restrict__ nB,
    const float* __restrict__ W2, const float* __restrict__ attS2, const float* __restrict__ attD2,
    float4* __restrict__ pk2)
{
    int wid  = (blockIdx.x * 256 + threadIdx.x) >> 6;
    int lane = threadIdx.x & 63;
    if (wid >= NN) return;
    int lo = offs[wid], hi = offs[wid + 1];
    const int ep   = lane >> 5;    // edge parity
    const int fl   = lane & 31;    // 8B block of row: feats fl*8 .. fl*8+7
    const int head = fl >> 3;

    float acc[8] = {0.f, 0.f, 0.f, 0.f, 0.f, 0.f, 0.f, 0.f};
    float wsum = 0.f;

    const uint2* h1v = (const uint2*)h1;   // row = 32 x uint2

    int base = lo;
    for (; base + 7 < hi; base += 8) {
        int idx0 = base + ep;
        int idx1 = base + 2 + ep;
        int idx2 = base + 4 + ep;
        int idx3 = base + 6 + ep;
        int4 e0 = csr[idx0];
        int4 e1 = csr[idx1];
        int4 e2 = csr[idx2];
        int4 e3 = csr[idx3];
        uint2 r0 = h1v[(size_t)e0.x * 32 + fl];
        uint2 r1 = h1v[(size_t)e1.x * 32 + fl];
        uint2 r2 = h1v[(size_t)e2.x * 32 + fl];
        uint2 r3 = h1v[(size_t)e3.x * 32 + fl];
        float w0 = ewgt(e0, head);
        float w1 = ewgt(e1, head);
        float w2 = ewgt(e2, head);
        float w3 = ewgt(e3, head);
        fma8_fp8(r0, w0, acc);
        fma8_fp8(r1, w1, acc);
        fma8_fp8(r2, w2, acc);
        fma8_fp8(r3, w3, acc);
        wsum += w0 + w1 + w2 + w3;
    }
    for (; base < hi; base += 2) {
        int idx = base + ep;
        float w = 0.f;
        uint2 r = make_uint2(0, 0);
        if (idx < hi) {
            int4 e = csr[idx];
            w = ewgt(e, head);
            r = h1v[(size_t)e.x * 32 + fl];
        }
        fma8_fp8(r, w, acc);
        wsum += w;
    }

    // merge edge-parity halves: after this, BOTH halves hold the full sums
#pragma unroll
    for (int j = 0; j < 8; j++) acc[j] += __shfl_xor(acc[j], 32);
    wsum += __shfl_xor(wsum, 32);

    float inv = 1.f / (wsum + 1e-16f);

    // fused node2 epilogue: lane fl holds feats fl*8..fl*8+7 (all 64 lanes duplicate)
    float c0 = 0.f, c1 = 0.f;
#pragma unroll
    for (int half8 = 0; half8 < 2; ++half8) {
        float4 na = *(const float4*)&nA[fl * 8 + half8 * 4];
        float4 nb = *(const float4*)&nB[fl * 8 + half8 * 4];
        float naa[4] = {na.x, na.y, na.z, na.w};
        float nba[4] = {nb.x, nb.y, nb.z, nb.w};
#pragma unroll
        for (int j = 0; j < 4; j++) {
            int f = fl * 8 + half8 * 4 + j;
            float g = acc[half8 * 4 + j] * inv;
            float u = fmaf(g, naa[j], nba[j]);
            float t = u > 0.f ? u : (__expf(u) - 1.f);
            c0 = fmaf(t, W2[f * 2],     c0);
            c1 = fmaf(t, W2[f * 2 + 1], c1);
        }
    }
    c0 += __shfl_xor(c0, 1); c0 += __shfl_xor(c0, 2); c0 += __shfl_xor(c0, 4);
    c0 += __shfl_xor(c0, 8); c0 += __shfl_xor(c0, 16);
    c1 += __shfl_xor(c1, 1); c1 += __shfl_xor(c1, 2); c1 += __shfl_xor(c1, 4);
    c1 += __shfl_xor(c1, 8); c1 += __shfl_xor(c1, 16);

    if (lane == 0) {
        float as2 = c0 * attS2[0] + c1 * attS2[1];
        float ad2 = c0 * attD2[0] + c1 * attD2[1];
        pk2[wid] = make_float4(as2, ad2, c0, c1);
    }
}

// ---------------- agg2: 8 lanes per node, 16B pk2 gather + fused log_softmax ----------------
__global__ __launch_bounds__(256) void agg2_kernel(
    const int* __restrict__ offs, const int4* __restrict__ csr,
    const float4* __restrict__ pk2, const float* __restrict__ b2,
    float* __restrict__ out)
{
    int wid  = (blockIdx.x * 256 + threadIdx.x) >> 6;
    int lane = threadIdx.x & 63;
    int grp  = lane >> 3;
    int sub  = lane & 7;
    int n = wid * 8 + grp;
    if (n >= NN) return;
    int lo = offs[n], hi = offs[n + 1];
    float ad = pk2[n].y;

    float n0 = 0.f, n1 = 0.f, ws = 0.f;
    for (int i = lo + sub; i < hi; i += 8) {
        int s = csr[i].x;
        float4 p = pk2[s];
        float w = __expf(lrelu(p.x + ad));
        n0 = fmaf(w, p.z, n0);
        n1 = fmaf(w, p.w, n1);
        ws += w;
    }
    n0 += __shfl_xor(n0, 1); n0 += __shfl_xor(n0, 2); n0 += __shfl_xor(n0, 4);
    n1 += __shfl_xor(n1, 1); n1 += __shfl_xor(n1, 2); n1 += __shfl_xor(n1, 4);
    ws += __shfl_xor(ws, 1); ws += __shfl_xor(ws, 2); ws += __shfl_xor(ws, 4);

    if (sub == 0) {
        float inv = 1.f / (ws + 1e-16f);
        float v0 = n0 * inv + b2[0];
        float v1 = n1 * inv + b2[1];
        float m = fmaxf(v0, v1);
        float lse = m + log1pf(__expf(fminf(v0, v1) - m));
        *(float2*)&out[(size_t)n * 2] = make_float2(v0 - lse, v1 - lse);
    }
}

extern "C" void kernel_launch(void* const* d_in, const int* in_sizes, int n_in,
                              void* d_out, int out_size, void* d_ws, size_t ws_size,
                              hipStream_t stream)
{
    const float* x     = (const float*)d_in[0];
    const int*   ei    = (const int*)d_in[1];
    const float* W1    = (const float*)d_in[2];
    const float* attS1 = (const float*)d_in[3];
    const float* attD1 = (const float*)d_in[4];
    const float* b1    = (const float*)d_in[5];
    const float* gamma = (const float*)d_in[6];
    const float* beta  = (const float*)d_in[7];
    const float* rmean = (const float*)d_in[8];
    const float* rvar  = (const float*)d_in[9];
    const float* W2    = (const float*)d_in[10];
    const float* attS2 = (const float*)d_in[11];
    const float* attD2 = (const float*)d_in[12];
    const float* b2    = (const float*)d_in[13];
    float* out = (float*)d_out;

    float* f = (float*)d_ws;
    uint* h1      = (uint*)f;                    // N*64 dwords (fp8 rows, 256B each)
    float* asrc1  = f + (size_t)NN * 64;         // N*4
    float* adst1  = asrc1 + (size_t)NN * 4;      // N*4
    _Float16* W1f = (_Float16*)(adst1 + (size_t)NN * 4);  // 32768 halfs = 16384 floats
    float* nA     = adst1 + (size_t)NN * 4 + 16384;       // 256
    float* nB     = nA + 256;                    // 256
    float4* pk2   = (float4*)(nB + 256);         // N float4 (16B aligned)
    int4* csr     = (int4*)(pk2 + NN);           // E int4  (16B aligned)
    int* counts   = (int*)(csr + EE);            // N [zeroed in prep]
    int* offs     = counts + NN;                 // N+1
    int* cursor   = offs + (NN + 1);             // N
    int* bsum     = cursor + NN;                 // NB
    int* bbase    = bsum + NB;                   // NB

    prep_kernel<<<128, 256, 0, stream>>>(W1, b1, gamma, beta, rmean, rvar, W1f, nA, nB, counts);

    gemm1_hist<<<GB + HB, 256, 0, stream>>>(x, W1f, attS1, attD1, h1, asrc1, adst1, ei, counts);

    scan1_kernel<<<NB, 256, 0, stream>>>(counts, bsum);
    scan2_kernel<<<1, 128, 0, stream>>>(bsum, bbase, offs);
    scan3_kernel<<<NB, 256, 0, stream>>>(counts, bbase, offs, cursor);

    scatter_kernel<<<HB, 256, 0, stream>>>(ei, asrc1, adst1, cursor, csr);

    agg1_node2<<<(NN + 3) / 4, 256, 0, stream>>>(offs, csr, h1, nA, nB, W2, attS2, attD2, pk2);

    agg2_kernel<<<(NN + 31) / 32, 256, 0, stream>>>(offs, csr, pk2, b2, out);
}